// Round 8
// baseline (1772.085 us; speedup 1.0000x reference)
//
#include <hip/hip_runtime.h>
#include <hip/hip_bf16.h>
#include <math.h>

typedef __bf16 bf16x8 __attribute__((ext_vector_type(8)));
typedef float f32x4 __attribute__((ext_vector_type(4)));
typedef unsigned short u16x8 __attribute__((ext_vector_type(8)));

__device__ inline unsigned short f2b(float f) {
  union { float f; unsigned u; } v; v.f = f;
  unsigned u = v.u;
  return (unsigned short)((u + 0x7fffu + ((u >> 16) & 1u)) >> 16);
}
__device__ inline float b2f(unsigned short s) {
  union { unsigned u; float f; } v; v.u = ((unsigned)s) << 16;
  return v.f;
}
__device__ inline float sigm(float x) { return 1.f / (1.f + __expf(-x)); }
__device__ inline float tanh_f(float x) {
  float e = __expf(2.f * x);
  return 1.f - 2.f / (e + 1.f);
}
// cached global->LDS 16B
__device__ inline void gll16(const unsigned short* g, unsigned short* l) {
  __builtin_amdgcn_global_load_lds(
      (const __attribute__((address_space(1))) void*)g,
      (__attribute__((address_space(3))) void*)l, 16, 0, 0);
}
// coherent (sc0|sc1) global->LDS 16B: bypasses L2 (no pollution), IF$ read
__device__ inline void gll16u(const unsigned short* g, unsigned short* l) {
  __builtin_amdgcn_global_load_lds(
      (const __attribute__((address_space(1))) void*)g,
      (__attribute__((address_space(3))) void*)l, 16, 0, 17);
}
__device__ inline void as64(unsigned short* p, unsigned long long v) {
  __hip_atomic_store((unsigned long long*)p, v, __ATOMIC_RELAXED,
                     __HIP_MEMORY_SCOPE_AGENT);
}

// -------------------- prep: weights->bf16, h init --------------------
__global__ __launch_bounds__(256) void prep_kernel(
    const float* __restrict__ Wih, const float* __restrict__ Whh,
    const float* __restrict__ c, unsigned short* __restrict__ Wihb,
    unsigned short* __restrict__ Whhb, unsigned short* __restrict__ hbf,
    float* __restrict__ h32, long nW, long nH)
{
  long stride = (long)gridDim.x * blockDim.x;
  long t0 = (long)blockIdx.x * blockDim.x + threadIdx.x;
  for (long i = t0; i < nW; i += stride) {
    Wihb[i] = f2b(Wih[i]);
    Whhb[i] = f2b(Whh[i]);
  }
  for (long i = t0; i < nH; i += stride) {
    float v = c[i];
    h32[i] = v;
    hbf[i] = f2b(v);
  }
}

// ---- reorder rows: row' = (g6*3+g)*64+elo  <-  row = g*E + g6*64 + elo ----
__global__ __launch_bounds__(256) void reorder_kernel(
    const unsigned short* __restrict__ Wihb, const unsigned short* __restrict__ Whhb,
    const float* __restrict__ bih, const float* __restrict__ bhh,
    unsigned short* __restrict__ Wihp, unsigned short* __restrict__ Whhp,
    float* __restrict__ bihp, float* __restrict__ bhhp, int E)
{
  int N3 = 3 * E;
  long total = (long)N3 * E;
  long stride = (long)gridDim.x * blockDim.x;
  long t0 = (long)blockIdx.x * blockDim.x + threadIdx.x;
  for (long i = t0; i < total; i += stride) {
    int rp = (int)(i / E);
    int col = (int)(i - (long)rp * E);
    int g6 = rp / 192, rem = rp - g6 * 192;
    int g = rem >> 6, elo = rem & 63;
    long src = ((long)g * E + g6 * 64 + elo) * E + col;
    Wihp[i] = Wihb[src];
    Whhp[i] = Whhb[src];
  }
  for (long i = t0; i < N3; i += stride) {
    int rp = (int)i;
    int g6 = rp / 192, rem = rp - g6 * 192;
    int g = rem >> 6, elo = rem & 63;
    bihp[i] = bih[(long)g * E + g6 * 64 + elo];
    bhhp[i] = bhh[(long)g * E + g6 * 64 + elo];
  }
}

// -------------------- transpose x (B,E,K) -> XS (K,B,E) bf16 ----------
__global__ __launch_bounds__(256) void transpose_x(
    const float* __restrict__ x, unsigned short* __restrict__ XS,
    int B, int E, int K)
{
  __shared__ float T[64][65];
  int e0 = blockIdx.x * 64;
  int b = blockIdx.y;
  int t = threadIdx.x;
  const float* xb = x + ((long)b * E + e0) * K;
#pragma unroll
  for (int i = 0; i < 4; ++i) {
    int cidx = i * 256 + t;
    int e = cidx >> 4;
    int f4 = cidx & 15;
    float4 v = *(const float4*)(xb + (long)e * K + f4 * 4);
    T[e][f4 * 4 + 0] = v.x;
    T[e][f4 * 4 + 1] = v.y;
    T[e][f4 * 4 + 2] = v.z;
    T[e][f4 * 4 + 3] = v.w;
  }
  __syncthreads();
#pragma unroll
  for (int i = 0; i < 16; ++i) {
    int cidx = i * 256 + t;
    int k = cidx >> 6;
    int e = cidx & 63;
    if (k < K - 1)
      XS[((long)(k + 1) * B + b) * E + e0 + e] = f2b(T[e][k]);
  }
}

// -------------------- GEMM: C(M,N) = A(M,K) @ Bw(N,K)^T + bias --------
#define BM 128
#define BN 128
#define BKS 64

template<int OUTBF>
__global__ __launch_bounds__(256)
void gemm_bt(const unsigned short* __restrict__ A,
             const unsigned short* __restrict__ Bw,
             const float* __restrict__ bias,
             float* __restrict__ Cf, unsigned short* __restrict__ Cb,
             int M, int N, int K)
{
  __shared__ __align__(16) unsigned short As[BM * BKS];
  __shared__ __align__(16) unsigned short Bs[BN * BKS];

  int nwg = gridDim.x * gridDim.y;
  int wg = blockIdx.y * gridDim.x + blockIdx.x;
  if ((nwg & 7) == 0) { int ch = nwg >> 3; wg = (wg & 7) * ch + (wg >> 3); }
  int tx = wg % gridDim.x;
  int ty = wg / gridDim.x;

  const int tid = threadIdx.x;
  const int lane = tid & 63;
  const int wave = tid >> 6;
  const int wr = wave >> 1, wc = wave & 1;

  f32x4 acc[4][4] = {};

  const long a_base = (long)ty * BM * K;
  const long b_base = (long)tx * BN * K;

  for (int kt = 0; kt < K; kt += BKS) {
    __syncthreads();
#pragma unroll
    for (int i = 0; i < 4; ++i) {
      int c = i * 256 + tid;
      int row = c >> 3, sc = c & 7;
      int gcol8 = sc ^ (row & 7);
      const unsigned short* ga = A + a_base + (long)row * K + kt + gcol8 * 8;
      const unsigned short* gb = Bw + b_base + (long)row * K + kt + gcol8 * 8;
      int cbase = (i * 256 + wave * 64) * 8;
      gll16(ga, &As[cbase]);
      gll16(gb, &Bs[cbase]);
    }
    __syncthreads();
#pragma unroll
    for (int kk = 0; kk < BKS; kk += 32) {
      int kidx = kk + ((lane >> 4) << 3);
      int c8 = kidx >> 3;
      bf16x8 af[4], bfv[4];
#pragma unroll
      for (int m = 0; m < 4; ++m) {
        int row = wr * 64 + m * 16 + (lane & 15);
        af[m] = *(const bf16x8*)&As[row * BKS + ((c8 ^ (row & 7)) << 3)];
      }
#pragma unroll
      for (int n = 0; n < 4; ++n) {
        int col = wc * 64 + n * 16 + (lane & 15);
        bfv[n] = *(const bf16x8*)&Bs[col * BKS + ((c8 ^ (col & 7)) << 3)];
      }
#pragma unroll
      for (int m = 0; m < 4; ++m)
#pragma unroll
        for (int n = 0; n < 4; ++n)
          acc[m][n] = __builtin_amdgcn_mfma_f32_16x16x32_bf16(
              af[m], bfv[n], acc[m][n], 0, 0, 0);
    }
  }

  long crow0 = (long)ty * BM + wr * 64;
  long ccol0 = (long)tx * BN + wc * 64;
#pragma unroll
  for (int m = 0; m < 4; ++m) {
#pragma unroll
    for (int n = 0; n < 4; ++n) {
      long col = ccol0 + n * 16 + (lane & 15);
      float bv = bias[col];
#pragma unroll
      for (int j = 0; j < 4; ++j) {
        long row = crow0 + m * 16 + ((lane >> 4) << 2) + j;
        float v = acc[m][n][j] + bv;
        if (OUTBF) Cb[row * N + col] = f2b(v);
        else       Cf[row * N + col] = v;
      }
    }
  }
}

// -------------------- persistent fused recurrence v5 ------------------
// As v4 plus: GI via L2-bypass loads, Y via bypass stores (L2 holds only
// Whh -> panel stays resident); cross-step prefetch of GI(k+1)+B(k+1,0/1)
// kept alive across the flag barrier via store-exact VMW(9) (in-order
// vmcnt retirement: 4 stores are oldest). B ring slot = (k+kt)%3 rotates
// continuously across steps. Raw-barrier epilogue, no full drains.
#define VMW(N) asm volatile("s_waitcnt vmcnt(" #N ")" ::: "memory")
#define LGKM0  asm volatile("s_waitcnt lgkmcnt(0)" ::: "memory")

__global__ __launch_bounds__(512, 1)
void gru_rec5(const unsigned short* __restrict__ GI,
              const unsigned short* __restrict__ Whp,
              const float* __restrict__ bhp,
              const unsigned short* __restrict__ h0,
              unsigned short* __restrict__ hbuf0,
              unsigned short* __restrict__ hbuf1,
              unsigned short* __restrict__ Y,
              unsigned int* __restrict__ bar,
              int B, int E, int K, int net)
{
  __shared__ __align__(16) unsigned char smem[156672];     // 153 KB
  unsigned short* Ah  = (unsigned short*)smem;             // 6 x 8KB A ring
  unsigned short* Bss = (unsigned short*)(smem + 49152);   // 3 x 24KB B ring
  unsigned short* GIs = (unsigned short*)(smem + 122880);  // 24KB
  unsigned short* Ys  = (unsigned short*)(smem + 147456);  // 9KB persistent h
  float* Red = (float*)smem;  // gate-phase alias (B slot0 head overwritten,
                              // restaged next step before any read)

  const int N3 = 3 * E;
  const int e6 = blockIdx.x;           // e6%8 -> XCD pinning of Whh panel
  const int bt = blockIdx.y;
  const int b0 = bt << 6;
  const int ec0 = e6 * 192;
  const int ecol0 = e6 << 6;
  const int tid = threadIdx.x;
  const int lane = tid & 63;
  const int w = tid >> 6;
  const int ew = w >> 1;
  const int kw = w & 1;
  const int q = lane >> 4;
  const int l15 = lane & 15;
  const int el = (ew << 4) + l15;
  const int c8 = (kw << 2) + q;
  const int axo = (c8 ^ (l15 & 7)) << 3;
  const int bxo = (c8 ^ (el & 7)) << 3;

  const int arow = tid >> 3;
  const int ag8 = (tid & 7) ^ (arow & 7);
  const long a_goff = (long)(b0 + arow) * E + ag8 * 8;
  const int a_dst = tid * 8;
  long b_goff[3]; int b_dst[3];
#pragma unroll
  for (int i = 0; i < 3; ++i) {
    int c = i * 512 + tid;
    int row = c >> 3;
    int g8 = (c & 7) ^ (row & 7);
    b_goff[i] = (long)(ec0 + row) * E + g8 * 8;
    b_dst[i] = c * 8;
  }
  long gi_off[3]; int gi_dst[3];
#pragma unroll
  for (int i = 0; i < 3; ++i) {
    int c = i * 512 + tid;
    int row = c / 24, cc = c - row * 24;
    gi_off[i] = (long)(b0 + row) * N3 + ec0 + cc * 8;
    gi_dst[i] = c * 8;
  }

  const float bh0 = bhp[ec0 + el];
  const float bh1 = bhp[ec0 + 64 + el];
  const float bh2 = bhp[ec0 + 128 + el];

  // Ys preload: persistent per-WG h cache (owned by kw==0 lanes)
  if (kw == 0) {
#pragma unroll
    for (int m = 0; m < 4; ++m)
#pragma unroll
      for (int j = 0; j < 4; ++j) {
        int row = m * 16 + q * 4 + j;
        Ys[row * 72 + el] = h0[(long)(b0 + row) * E + ecol0 + el];
      }
  }
  __syncthreads();

  // ---- pre-loop: GI(0) bypass, B(0,0)->slot0, B(0,1)->slot1 ----
#pragma unroll
  for (int i = 0; i < 3; ++i) gll16u(GI + gi_off[i], GIs + gi_dst[i]);
#pragma unroll
  for (int i = 0; i < 3; ++i) gll16(Whp + b_goff[i], Bss + b_dst[i]);
#pragma unroll
  for (int i = 0; i < 3; ++i) gll16(Whp + b_goff[i] + 64, Bss + 12288 + b_dst[i]);

  for (int k = 0; k < K; ++k) {
    const unsigned short* hprev = (k & 1) ? hbuf1 : hbuf0;
    unsigned short* hnext = (k & 1) ? hbuf0 : hbuf1;

    // ---- prolog: A tiles 0..4 only (h-dependent; rest already in flight)
#pragma unroll
    for (int t = 0; t < 5; ++t)
      gll16u(hprev + a_goff + t * 64, Ah + t * 4096 + a_dst);

    f32x4 acc[4][3];
#pragma unroll
    for (int m = 0; m < 4; ++m)
#pragma unroll
      for (int g = 0; g < 3; ++g)
        acc[m][g] = (f32x4){0.f, 0.f, 0.f, 0.f};

#pragma unroll
    for (int kt = 0; kt < 16; ++kt) {
      // exact waits (in-order vmcnt): outstanding at kt0 = GI(3)+B0(3)+
      // B1(3)+A0..4(5); newest-needed drives the count.
      if (kt == 0)       VMW(4);
      else if (kt == 1)  VMW(7);
      else if (kt <= 11) VMW(5);
      else if (kt == 12) VMW(4);
      else if (kt == 15) VMW(0);
      else               VMW(3);
      LGKM0;
      __builtin_amdgcn_s_barrier();
      asm volatile("" ::: "memory");

      if (kt <= 13) {   // stage B(k,kt+2) -> slot (k+kt+2)%3
        int sl = (k + kt + 2) % 3;
#pragma unroll
        for (int i = 0; i < 3; ++i)
          gll16(Whp + b_goff[i] + (kt + 2) * 64, Bss + sl * 12288 + b_dst[i]);
      }
      if (kt <= 10)
        gll16u(hprev + a_goff + (kt + 5) * 64, Ah + ((kt + 5) % 6) * 4096 + a_dst);

      const unsigned short* Ab = Ah + (kt % 6) * 4096;
      const unsigned short* Bb = Bss + ((k + kt) % 3) * 12288;
      bf16x8 af[4], bfg[3];
#pragma unroll
      for (int m = 0; m < 4; ++m)
        af[m] = *(const bf16x8*)&Ab[(m * 16 + l15) * 64 + axo];
#pragma unroll
      for (int g = 0; g < 3; ++g)
        bfg[g] = *(const bf16x8*)&Bb[(g * 64 + el) * 64 + bxo];

      __builtin_amdgcn_s_setprio(1);
#pragma unroll
      for (int g = 0; g < 3; ++g)
#pragma unroll
        for (int m = 0; m < 4; ++m)
          acc[m][g] = __builtin_amdgcn_mfma_f32_16x16x32_bf16(
              af[m], bfg[g], acc[m][g], 0, 0, 0);
      __builtin_amdgcn_s_setprio(0);
    }

    // ---- epilogue: raw barriers, exact drains ----
    LGKM0;
    __builtin_amdgcn_s_barrier();      // all waves done reading A/B LDS
    asm volatile("" ::: "memory");
    float* rp = &Red[((ew << 6) + lane) * 49];
    if (kw == 1) {
#pragma unroll
      for (int m = 0; m < 4; ++m)
#pragma unroll
        for (int g = 0; g < 3; ++g)
#pragma unroll
          for (int cc = 0; cc < 4; ++cc)
            rp[(m * 3 + g) * 4 + cc] = acc[m][g][cc];
    }
    LGKM0;
    __builtin_amdgcn_s_barrier();
    asm volatile("" ::: "memory");
    if (kw == 0) {
#pragma unroll
      for (int m = 0; m < 4; ++m) {
#pragma unroll
        for (int j = 0; j < 4; ++j) {
          int row = m * 16 + q * 4 + j;
          float ghr = acc[m][0][j] + rp[(m * 3 + 0) * 4 + j];
          float ghz = acc[m][1][j] + rp[(m * 3 + 1) * 4 + j];
          float ghn = acc[m][2][j] + rp[(m * 3 + 2) * 4 + j];
          float gr = b2f(GIs[row * 192 + el]);
          float gz = b2f(GIs[row * 192 + 64 + el]);
          float gn = b2f(GIs[row * 192 + 128 + el]);
          float hu = b2f(Ys[row * 72 + el]);
          float r = sigm(gr + ghr + bh0);
          float z = sigm(gz + ghz + bh1);
          float n = tanh_f(gn + r * (ghn + bh2));
          float hv = (1.f - z) * n + z * hu;
          Ys[row * 72 + el] = f2b(hv);
        }
      }
    }
    LGKM0;
    __builtin_amdgcn_s_barrier();
    asm volatile("" ::: "memory");
    // ---- write-out (bypass stores; oldest in vmem queue) ----
    {
      int row = tid >> 3, cc = tid & 7;
      u16x8 v = *(const u16x8*)&Ys[row * 72 + cc * 8];
      unsigned* pv = (unsigned*)&v;
      unsigned long long s0 = ((unsigned long long)pv[1] << 32) | pv[0];
      unsigned long long s1 = ((unsigned long long)pv[3] << 32) | pv[2];
      unsigned short* hp = hnext + (long)(b0 + row) * E + ecol0 + cc * 8;
      as64(hp, s0);
      as64(hp + 4, s1);
      unsigned short* yp = Y + ((long)k * B + b0 + row) * E + ecol0 + cc * 8;
      as64(yp, s0);
      as64(yp + 4, s1);
    }
    if (k + 1 < K) {
      // cross-step prefetch: GI(k+1) bypass + B(k+1,0/1) cached
      const unsigned short* GIn = GI + (long)(k + 1) * B * N3;
#pragma unroll
      for (int i = 0; i < 3; ++i) gll16u(GIn + gi_off[i], GIs + gi_dst[i]);
      int sl0 = (k + 1) % 3, sl1 = (k + 2) % 3;
#pragma unroll
      for (int i = 0; i < 3; ++i)
        gll16(Whp + b_goff[i], Bss + sl0 * 12288 + b_dst[i]);
#pragma unroll
      for (int i = 0; i < 3; ++i)
        gll16(Whp + b_goff[i] + 64, Bss + sl1 * 12288 + b_dst[i]);
      VMW(9);   // drains exactly the 4 stores; 9 prefetch loads stay live
      __builtin_amdgcn_s_barrier();
      asm volatile("" ::: "memory");
      if (tid == 0) {
        __hip_atomic_fetch_add(&bar[bt * 64], 1u, __ATOMIC_RELAXED,
                               __HIP_MEMORY_SCOPE_AGENT);
        unsigned target = (unsigned)(k + 1) * (unsigned)net;
        while (__hip_atomic_load(&bar[bt * 64], __ATOMIC_RELAXED,
                                 __HIP_MEMORY_SCOPE_AGENT) < target)
          __builtin_amdgcn_s_sleep(1);
      }
      __builtin_amdgcn_s_barrier();
      asm volatile("" ::: "memory");
    }
  }
}

// -------------------- pointwise GRU gates (fallback path) -------------
template<int YMODE>
__global__ __launch_bounds__(256)
void gru_pointwise(const unsigned short* __restrict__ GIk,
                   const float* __restrict__ gh,
                   float* __restrict__ h, unsigned short* __restrict__ hbf,
                   unsigned short* __restrict__ Yb,
                   float* __restrict__ out, int k, int B, int E, int K)
{
  long i4 = ((long)blockIdx.x * blockDim.x + threadIdx.x) * 4;
  if (i4 >= (long)B * E) return;
  long b = i4 / E;
  long e = i4 - b * E;
  long g0 = b * 3 * E + e;
  ushort4 ir = *(const ushort4*)(GIk + g0);
  ushort4 iz = *(const ushort4*)(GIk + g0 + E);
  ushort4 in4 = *(const ushort4*)(GIk + g0 + 2 * E);
  float4 hr = *(const float4*)(gh + g0);
  float4 hz = *(const float4*)(gh + g0 + E);
  float4 hn = *(const float4*)(gh + g0 + 2 * E);
  float4 hv = *(const float4*)(h + i4);

  float irf[4] = { b2f(ir.x), b2f(ir.y), b2f(ir.z), b2f(ir.w) };
  float izf[4] = { b2f(iz.x), b2f(iz.y), b2f(iz.z), b2f(iz.w) };
  float inf_[4] = { b2f(in4.x), b2f(in4.y), b2f(in4.z), b2f(in4.w) };
  float hrf[4] = { hr.x, hr.y, hr.z, hr.w };
  float hzf[4] = { hz.x, hz.y, hz.z, hz.w };
  float hnf[4] = { hn.x, hn.y, hn.z, hn.w };
  float hvf[4] = { hv.x, hv.y, hv.z, hv.w };
  float hnew[4];
#pragma unroll
  for (int j = 0; j < 4; ++j) {
    float r = sigm(irf[j] + hrf[j]);
    float z = sigm(izf[j] + hzf[j]);
    float n = tanh_f(inf_[j] + r * hnf[j]);
    hnew[j] = (1.f - z) * n + z * hvf[j];
  }
  *(float4*)(h + i4) = make_float4(hnew[0], hnew[1], hnew[2], hnew[3]);
  ushort4 hb = make_ushort4(f2b(hnew[0]), f2b(hnew[1]), f2b(hnew[2]), f2b(hnew[3]));
  *(ushort4*)(hbf + i4) = hb;
  if (YMODE == 1) {
    *(ushort4*)(Yb + ((long)k * B + b) * E + e) = hb;
  } else {
    float* o = out + (b * E + e) * K + k;
    o[0] = hnew[0]; o[K] = hnew[1]; o[2 * K] = hnew[2]; o[3 * K] = hnew[3];
  }
}

// -------------------- transpose Y (K,B,E) bf16 -> out (B,E,K) fp32 ----
__global__ __launch_bounds__(256)
void transpose_y(const unsigned short* __restrict__ Yv, float* __restrict__ out,
                 int B, int E, int K)
{
  __shared__ float T[64][65];
  int e0 = blockIdx.x * 64;
  int b = blockIdx.y;
  int t = threadIdx.x;
#pragma unroll
  for (int i = 0; i < 4; ++i) {
    int c = i * 256 + t;
    int k = c >> 4, f4 = c & 15;
    long off = ((long)k * B + b) * E + e0 + f4 * 4;
    ushort4 v = *(const ushort4*)(Yv + off);
    T[k][f4 * 4 + 0] = b2f(v.x); T[k][f4 * 4 + 1] = b2f(v.y);
    T[k][f4 * 4 + 2] = b2f(v.z); T[k][f4 * 4 + 3] = b2f(v.w);
  }
  __syncthreads();
#pragma unroll
  for (int i = 0; i < 4; ++i) {
    int c = i * 256 + t;
    int e = c >> 4, f4k = c & 15;
    float4 w;
    w.x = T[f4k * 4 + 0][e];
    w.y = T[f4k * 4 + 1][e];
    w.z = T[f4k * 4 + 2][e];
    w.w = T[f4k * 4 + 3][e];
    *(float4*)(out + ((long)b * E + e0 + e) * K + f4k * 4) = w;
  }
}

// -------------------- host launch -------------------------------------
extern "C" void kernel_launch(void* const* d_in, const int* in_sizes, int n_in,
                              void* d_out, int out_size, void* d_ws, size_t ws_size,
                              hipStream_t stream)
{
  const float* c   = (const float*)d_in[0];
  const float* x   = (const float*)d_in[1];
  const float* Wih = (const float*)d_in[2];
  const float* Whh = (const float*)d_in[3];
  const float* bih = (const float*)d_in[4];
  const float* bhh = (const float*)d_in[5];
  float* out = (float*)d_out;

  long BE = in_sizes[0];
  int E = (int)(sqrtf((float)(in_sizes[2] / 3)) + 0.5f);
  int B = (int)(BE / E);
  int K = (int)(in_sizes[1] / BE);
  int N3 = 3 * E;
  long M_GI = (long)K * B;

  char* w = (char*)d_ws;
  size_t used = 0;
  auto alloc = [&](size_t bytes) -> char* {
    char* p = w + used;
    used += (bytes + 255) & ~(size_t)255;
    return p;
  };
  unsigned short* Wihb  = (unsigned short*)alloc((size_t)N3 * E * 2);
  unsigned short* Whhb  = (unsigned short*)alloc((size_t)N3 * E * 2);
  unsigned short* hb0   = (unsigned short*)alloc((size_t)B * E * 2);
  float* h32            = (float*)alloc((size_t)B * E * 4);
  float* gh             = (float*)alloc((size_t)B * N3 * 4);
  unsigned short* GIstep= (unsigned short*)alloc((size_t)B * N3 * 2);
  unsigned short* XS    = (unsigned short*)alloc((size_t)K * B * E * 2);

  size_t rem = (ws_size > used) ? ws_size - used : 0;
  size_t szW   = (((size_t)N3 * E * 2) + 255) & ~(size_t)255;
  size_t szB3  = (((size_t)N3 * 4) + 255) & ~(size_t)255;
  size_t szHb1 = (((size_t)B * E * 2) + 255) & ~(size_t)255;
  size_t szGI  = (((size_t)K * B * N3 * 2) + 255) & ~(size_t)255;
  size_t szY   = (((size_t)K * B * E * 2) + 255) & ~(size_t)255;
  int nbt = B / 64, net = E / 64;
  size_t szBar = ((size_t)nbt * 64 * 4 + 255) & ~(size_t)255;

  bool canFused = (B == 1024) && (E == 1024) &&
                  (rem >= 2 * szW + 2 * szB3 + szHb1 + szGI + szY + szBar);

  long nW = (long)N3 * E;
  prep_kernel<<<dim3(2048), dim3(256), 0, stream>>>(Wih, Whh, c, Wihb, Whhb,
                                                    hb0, h32, nW, BE);
  hipMemsetAsync(XS, 0, (size_t)B * E * 2, stream);
  transpose_x<<<dim3(E / 64, B), dim3(256), 0, stream>>>(x, XS, B, E, K);

  if (canFused) {
    unsigned short* Wihp = (unsigned short*)alloc(szW);
    unsigned short* Whhp = (unsigned short*)alloc(szW);
    float* bihp          = (float*)alloc(szB3);
    float* bhhp          = (float*)alloc(szB3);
    unsigned short* hb1  = (unsigned short*)alloc(szHb1);
    unsigned short* GI   = (unsigned short*)alloc(szGI);
    unsigned short* Yb   = (unsigned short*)alloc(szY);
    unsigned int*   bar  = (unsigned int*)alloc(szBar);

    reorder_kernel<<<dim3(2048), dim3(256), 0, stream>>>(
        Wihb, Whhb, bih, bhh, Wihp, Whhp, bihp, bhhp, E);

    gemm_bt<1><<<dim3(N3 / BN, (int)(M_GI / BM)), dim3(256), 0, stream>>>(
        XS, Wihp, bihp, nullptr, GI, (int)M_GI, N3, E);
    hipMemsetAsync(bar, 0, szBar, stream);

    const unsigned short* GIc = GI;
    const unsigned short* Whhc = Whhp;
    const float* bhhc = bhhp;
    const unsigned short* h0c = hb0;
    void* args[] = { (void*)&GIc, (void*)&Whhc, (void*)&bhhc, (void*)&h0c,
                     (void*)&hb0, (void*)&hb1, (void*)&Yb,
                     (void*)&bar, (void*)&B, (void*)&E, (void*)&K, (void*)&net };
    hipError_t ce = hipLaunchCooperativeKernel(
        (const void*)gru_rec5, dim3(net, nbt), dim3(512), args, 0, stream);
    if (ce != hipSuccess) {
      (void)hipGetLastError();
      gru_rec5<<<dim3(net, nbt), dim3(512), 0, stream>>>(
          GIc, Whhc, bhhc, h0c, hb0, hb1, Yb, bar, B, E, K, net);
    }
    transpose_y<<<dim3(E / 64, B), dim3(256), 0, stream>>>(Yb, out, B, E, K);
    return;
  }

  // -------- fallback: per-step GEMMs (round-1 path, normal layout) -----
  int haveY = rem >= szY;
  unsigned short* Yb = haveY ? (unsigned short*)alloc(szY) : nullptr;
  int pgrid = (int)((BE / 4 + 255) / 256);
  for (int k = 0; k < K; ++k) {
    gemm_bt<1><<<dim3(N3 / BN, B / BM), dim3(256), 0, stream>>>(
        XS + (size_t)k * B * E, Wihb, bih, nullptr, GIstep, B, N3, E);
    gemm_bt<0><<<dim3(N3 / BN, B / BM), dim3(256), 0, stream>>>(
        hb0, Whhb, bhh, gh, nullptr, B, N3, E);
    if (haveY)
      gru_pointwise<1><<<dim3(pgrid), dim3(256), 0, stream>>>(
          GIstep, gh, h32, hb0, Yb, out, k, B, E, K);
    else
      gru_pointwise<2><<<dim3(pgrid), dim3(256), 0, stream>>>(
          GIstep, gh, h32, hb0, nullptr, out, k, B, E, K);
  }
  if (haveY)
    transpose_y<<<dim3(E / 64, B), dim3(256), 0, stream>>>(Yb, out, B, E, K);
}

// Round 9
// 1480.017 us; speedup vs baseline: 1.1973x; 1.1973x over previous
//
#include <hip/hip_runtime.h>
#include <hip/hip_bf16.h>
#include <math.h>

typedef __bf16 bf16x8 __attribute__((ext_vector_type(8)));
typedef float f32x4 __attribute__((ext_vector_type(4)));
typedef unsigned short u16x8 __attribute__((ext_vector_type(8)));

#define VMW(N) asm volatile("s_waitcnt vmcnt(" #N ")" ::: "memory")
#define LGKM0  asm volatile("s_waitcnt lgkmcnt(0)" ::: "memory")
#define CFENCE asm volatile("" ::: "memory")

__device__ inline unsigned short f2b(float f) {
  union { float f; unsigned u; } v; v.f = f;
  unsigned u = v.u;
  return (unsigned short)((u + 0x7fffu + ((u >> 16) & 1u)) >> 16);
}
__device__ inline float b2f(unsigned short s) {
  union { unsigned u; float f; } v; v.u = ((unsigned)s) << 16;
  return v.f;
}
__device__ inline float sigm(float x) { return 1.f / (1.f + __expf(-x)); }
__device__ inline float tanh_f(float x) {
  float e = __expf(2.f * x);
  return 1.f - 2.f / (e + 1.f);
}
// cached global->LDS 16B
__device__ inline void gll16(const unsigned short* g, unsigned short* l) {
  __builtin_amdgcn_global_load_lds(
      (const __attribute__((address_space(1))) void*)g,
      (__attribute__((address_space(3))) void*)l, 16, 0, 0);
}
// coherent (sc0|sc1) global->LDS 16B (IF$-coherent, for the h exchange)
__device__ inline void gll16u(const unsigned short* g, unsigned short* l) {
  __builtin_amdgcn_global_load_lds(
      (const __attribute__((address_space(1))) void*)g,
      (__attribute__((address_space(3))) void*)l, 16, 0, 17);
}
__device__ inline void as64(unsigned short* p, unsigned long long v) {
  __hip_atomic_store((unsigned long long*)p, v, __ATOMIC_RELAXED,
                     __HIP_MEMORY_SCOPE_AGENT);
}

// -------------------- prep: weights->bf16, h init --------------------
__global__ __launch_bounds__(256) void prep_kernel(
    const float* __restrict__ Wih, const float* __restrict__ Whh,
    const float* __restrict__ c, unsigned short* __restrict__ Wihb,
    unsigned short* __restrict__ Whhb, unsigned short* __restrict__ hbf,
    float* __restrict__ h32, long nW, long nH)
{
  long stride = (long)gridDim.x * blockDim.x;
  long t0 = (long)blockIdx.x * blockDim.x + threadIdx.x;
  for (long i = t0; i < nW; i += stride) {
    Wihb[i] = f2b(Wih[i]);
    Whhb[i] = f2b(Whh[i]);
  }
  for (long i = t0; i < nH; i += stride) {
    float v = c[i];
    h32[i] = v;
    hbf[i] = f2b(v);
  }
}

// ---- reorder rows: row' = (g6*3+g)*64+elo  <-  row = g*E + g6*64 + elo ----
__global__ __launch_bounds__(256) void reorder_kernel(
    const unsigned short* __restrict__ Wihb, const unsigned short* __restrict__ Whhb,
    const float* __restrict__ bih, const float* __restrict__ bhh,
    unsigned short* __restrict__ Wihp, unsigned short* __restrict__ Whhp,
    float* __restrict__ bihp, float* __restrict__ bhhp, int E)
{
  int N3 = 3 * E;
  long total = (long)N3 * E;
  long stride = (long)gridDim.x * blockDim.x;
  long t0 = (long)blockIdx.x * blockDim.x + threadIdx.x;
  for (long i = t0; i < total; i += stride) {
    int rp = (int)(i / E);
    int col = (int)(i - (long)rp * E);
    int g6 = rp / 192, rem = rp - g6 * 192;
    int g = rem >> 6, elo = rem & 63;
    long src = ((long)g * E + g6 * 64 + elo) * E + col;
    Wihp[i] = Wihb[src];
    Whhp[i] = Whhb[src];
  }
  for (long i = t0; i < N3; i += stride) {
    int rp = (int)i;
    int g6 = rp / 192, rem = rp - g6 * 192;
    int g = rem >> 6, elo = rem & 63;
    bihp[i] = bih[(long)g * E + g6 * 64 + elo];
    bhhp[i] = bhh[(long)g * E + g6 * 64 + elo];
  }
}

// -------------------- transpose x (B,E,K) -> XS (K,B,E) bf16 ----------
__global__ __launch_bounds__(256) void transpose_x(
    const float* __restrict__ x, unsigned short* __restrict__ XS,
    int B, int E, int K)
{
  __shared__ float T[64][65];
  int e0 = blockIdx.x * 64;
  int b = blockIdx.y;
  int t = threadIdx.x;
  const float* xb = x + ((long)b * E + e0) * K;
#pragma unroll
  for (int i = 0; i < 4; ++i) {
    int cidx = i * 256 + t;
    int e = cidx >> 4;
    int f4 = cidx & 15;
    float4 v = *(const float4*)(xb + (long)e * K + f4 * 4);
    T[e][f4 * 4 + 0] = v.x;
    T[e][f4 * 4 + 1] = v.y;
    T[e][f4 * 4 + 2] = v.z;
    T[e][f4 * 4 + 3] = v.w;
  }
  __syncthreads();
#pragma unroll
  for (int i = 0; i < 16; ++i) {
    int cidx = i * 256 + t;
    int k = cidx >> 6;
    int e = cidx & 63;
    if (k < K - 1)
      XS[((long)(k + 1) * B + b) * E + e0 + e] = f2b(T[e][k]);
  }
}

// ---------- gemm256: C(M,N)=A(M,K)@Bw(N,K)^T + bias, bf16 out --------
// BM=128, BN=256, BK=64, 512 thr (8 waves: 2M x 4N), ring-3 LDS,
// stage-distance 2, counted vmcnt(6) once per K-tile (never 0 in loop),
// two phases per tile (h=0/1, 16 MFMA each) with raw barriers + setprio.
__global__ __launch_bounds__(512, 1)
void gemm256(const unsigned short* __restrict__ A,
             const unsigned short* __restrict__ Bw,
             const float* __restrict__ bias,
             unsigned short* __restrict__ Cb,
             int M, int N, int K)
{
  __shared__ __align__(16) unsigned short sm[3 * 24576];  // 144 KB
  // slot s: A = sm + s*24576 (8192 ushorts), B = +8192 (16384 ushorts)

  int nwg = gridDim.x * gridDim.y;
  int wg = blockIdx.y * gridDim.x + blockIdx.x;
  if ((nwg & 7) == 0) { int ch = nwg >> 3; wg = (wg & 7) * ch + (wg >> 3); }
  int tx = wg % gridDim.x;   // N tile (256)
  int ty = wg / gridDim.x;   // M tile (128)

  const int tid = threadIdx.x;
  const int lane = tid & 63;
  const int wave = tid >> 6;
  const int wm = wave >> 2;        // 0..1
  const int wn = wave & 3;         // 0..3
  const int q = lane >> 4;
  const int l15 = lane & 15;

  const long a_base = (long)ty * 128 * K;
  const long b_base = (long)tx * 256 * K;

  // staging offsets: A 2 chunks, B 4 chunks of 16B per thread per tile
  long a_src[2]; int a_dst[2];
#pragma unroll
  for (int i = 0; i < 2; ++i) {
    int c = i * 512 + tid;
    int row = c >> 3;
    int g8 = (c & 7) ^ (row & 7);
    a_src[i] = a_base + (long)row * K + g8 * 8;
    a_dst[i] = c * 8;
  }
  long b_src[4]; int b_dst[4];
#pragma unroll
  for (int i = 0; i < 4; ++i) {
    int c = i * 512 + tid;
    int row = c >> 3;
    int g8 = (c & 7) ^ (row & 7);
    b_src[i] = b_base + (long)row * K + g8 * 8;
    b_dst[i] = c * 8;
  }

  // frag read offsets (ushort idx within slot)
  int a_ro[4], b_ro[4];
#pragma unroll
  for (int mi = 0; mi < 4; ++mi) {
    int lr = wm * 64 + mi * 16 + l15;
    a_ro[mi] = lr * 64;                    // + ((c8^(lr&7))<<3)
  }
#pragma unroll
  for (int ni = 0; ni < 4; ++ni) {
    int col = wn * 64 + ni * 16 + l15;
    b_ro[ni] = col * 64;
  }

  f32x4 acc[4][4] = {};

  const int NT = K >> 6;   // 16 for K=1024
  // prologue: stage tiles 0 and 1
#pragma unroll
  for (int t = 0; t < 2; ++t) {
    unsigned short* As = sm + t * 24576;
    unsigned short* Bs = As + 8192;
#pragma unroll
    for (int i = 0; i < 2; ++i) gll16(A + a_src[i] + t * 64, As + a_dst[i]);
#pragma unroll
    for (int i = 0; i < 4; ++i) gll16(Bw + b_src[i] + t * 64, Bs + b_dst[i]);
  }

  for (int kt = 0; kt < NT; ++kt) {
    if (kt >= NT - 2) VMW(0); else VMW(6);
    __builtin_amdgcn_s_barrier();
    CFENCE;
    const unsigned short* As = sm + (kt % 3) * 24576;
    const unsigned short* Bs = As + 8192;
    unsigned short* As2 = sm + ((kt + 2) % 3) * 24576;
    unsigned short* Bs2 = As2 + 8192;
    const bool st = (kt + 2 < NT);
    const int ko = (kt + 2) * 64;

    // ---- phase 0: stage A0,A1,B0 ; frags h=0 ; 16 MFMA ----
    if (st) {
      gll16(A + a_src[0] + ko, As2 + a_dst[0]);
      gll16(A + a_src[1] + ko, As2 + a_dst[1]);
      gll16(Bw + b_src[0] + ko, Bs2 + b_dst[0]);
    }
    {
      const int c8 = q;                  // h=0
      bf16x8 af[4], bf_[4];
#pragma unroll
      for (int mi = 0; mi < 4; ++mi) {
        int lr = wm * 64 + mi * 16 + l15;
        af[mi] = *(const bf16x8*)&As[a_ro[mi] + ((c8 ^ (lr & 7)) << 3)];
      }
#pragma unroll
      for (int ni = 0; ni < 4; ++ni) {
        int col = wn * 64 + ni * 16 + l15;
        bf_[ni] = *(const bf16x8*)&Bs[b_ro[ni] + ((c8 ^ (col & 7)) << 3)];
      }
      __builtin_amdgcn_s_setprio(1);
#pragma unroll
      for (int mi = 0; mi < 4; ++mi)
#pragma unroll
        for (int ni = 0; ni < 4; ++ni)
          acc[mi][ni] = __builtin_amdgcn_mfma_f32_16x16x32_bf16(
              af[mi], bf_[ni], acc[mi][ni], 0, 0, 0);
      __builtin_amdgcn_s_setprio(0);
    }
    LGKM0;
    __builtin_amdgcn_s_barrier();
    CFENCE;
    // ---- phase 1: stage B1,B2,B3 ; frags h=1 ; 16 MFMA ----
    if (st) {
      gll16(Bw + b_src[1] + ko, Bs2 + b_dst[1]);
      gll16(Bw + b_src[2] + ko, Bs2 + b_dst[2]);
      gll16(Bw + b_src[3] + ko, Bs2 + b_dst[3]);
    }
    {
      const int c8 = 4 + q;              // h=1
      bf16x8 af[4], bf_[4];
#pragma unroll
      for (int mi = 0; mi < 4; ++mi) {
        int lr = wm * 64 + mi * 16 + l15;
        af[mi] = *(const bf16x8*)&As[a_ro[mi] + ((c8 ^ (lr & 7)) << 3)];
      }
#pragma unroll
      for (int ni = 0; ni < 4; ++ni) {
        int col = wn * 64 + ni * 16 + l15;
        bf_[ni] = *(const bf16x8*)&Bs[b_ro[ni] + ((c8 ^ (col & 7)) << 3)];
      }
      __builtin_amdgcn_s_setprio(1);
#pragma unroll
      for (int mi = 0; mi < 4; ++mi)
#pragma unroll
        for (int ni = 0; ni < 4; ++ni)
          acc[mi][ni] = __builtin_amdgcn_mfma_f32_16x16x32_bf16(
              af[mi], bf_[ni], acc[mi][ni], 0, 0, 0);
      __builtin_amdgcn_s_setprio(0);
    }
    LGKM0;
  }

  // ---- epilogue ----
  long crow0 = (long)ty * 128 + wm * 64;
  long ccol0 = (long)tx * 256 + wn * 64;
#pragma unroll
  for (int mi = 0; mi < 4; ++mi) {
#pragma unroll
    for (int ni = 0; ni < 4; ++ni) {
      long col = ccol0 + ni * 16 + l15;
      float bv = bias[col];
#pragma unroll
      for (int j = 0; j < 4; ++j) {
        long row = crow0 + mi * 16 + (q << 2) + j;
        Cb[row * N + col] = f2b(acc[mi][ni][j] + bv);
      }
    }
  }
}

// -------------------- GEMM (fallback path): 128x128 m97-style ---------
#define BM 128
#define BN 128
#define BKS 64

template<int OUTBF>
__global__ __launch_bounds__(256)
void gemm_bt(const unsigned short* __restrict__ A,
             const unsigned short* __restrict__ Bw,
             const float* __restrict__ bias,
             float* __restrict__ Cf, unsigned short* __restrict__ Cb,
             int M, int N, int K)
{
  __shared__ __align__(16) unsigned short As[BM * BKS];
  __shared__ __align__(16) unsigned short Bs[BN * BKS];

  int nwg = gridDim.x * gridDim.y;
  int wg = blockIdx.y * gridDim.x + blockIdx.x;
  if ((nwg & 7) == 0) { int ch = nwg >> 3; wg = (wg & 7) * ch + (wg >> 3); }
  int tx = wg % gridDim.x;
  int ty = wg / gridDim.x;

  const int tid = threadIdx.x;
  const int lane = tid & 63;
  const int wave = tid >> 6;
  const int wr = wave >> 1, wc = wave & 1;

  f32x4 acc[4][4] = {};

  const long a_base = (long)ty * BM * K;
  const long b_base = (long)tx * BN * K;

  for (int kt = 0; kt < K; kt += BKS) {
    __syncthreads();
#pragma unroll
    for (int i = 0; i < 4; ++i) {
      int c = i * 256 + tid;
      int row = c >> 3, sc = c & 7;
      int gcol8 = sc ^ (row & 7);
      const unsigned short* ga = A + a_base + (long)row * K + kt + gcol8 * 8;
      const unsigned short* gb = Bw + b_base + (long)row * K + kt + gcol8 * 8;
      int cbase = (i * 256 + wave * 64) * 8;
      gll16(ga, &As[cbase]);
      gll16(gb, &Bs[cbase]);
    }
    __syncthreads();
#pragma unroll
    for (int kk = 0; kk < BKS; kk += 32) {
      int kidx = kk + ((lane >> 4) << 3);
      int c8 = kidx >> 3;
      bf16x8 af[4], bfv[4];
#pragma unroll
      for (int m = 0; m < 4; ++m) {
        int row = wr * 64 + m * 16 + (lane & 15);
        af[m] = *(const bf16x8*)&As[row * BKS + ((c8 ^ (row & 7)) << 3)];
      }
#pragma unroll
      for (int n = 0; n < 4; ++n) {
        int col = wc * 64 + n * 16 + (lane & 15);
        bfv[n] = *(const bf16x8*)&Bs[col * BKS + ((c8 ^ (col & 7)) << 3)];
      }
#pragma unroll
      for (int m = 0; m < 4; ++m)
#pragma unroll
        for (int n = 0; n < 4; ++n)
          acc[m][n] = __builtin_amdgcn_mfma_f32_16x16x32_bf16(
              af[m], bfv[n], acc[m][n], 0, 0, 0);
    }
  }

  long crow0 = (long)ty * BM + wr * 64;
  long ccol0 = (long)tx * BN + wc * 64;
#pragma unroll
  for (int m = 0; m < 4; ++m) {
#pragma unroll
    for (int n = 0; n < 4; ++n) {
      long col = ccol0 + n * 16 + (lane & 15);
      float bv = bias[col];
#pragma unroll
      for (int j = 0; j < 4; ++j) {
        long row = crow0 + m * 16 + ((lane >> 4) << 2) + j;
        float v = acc[m][n][j] + bv;
        if (OUTBF) Cb[row * N + col] = f2b(v);
        else       Cf[row * N + col] = v;
      }
    }
  }
}

// -------------------- persistent fused recurrence v4 (R7, verbatim) ---
__global__ __launch_bounds__(512, 1)
void gru_rec4(const unsigned short* __restrict__ GI,
              const unsigned short* __restrict__ Whp,
              const float* __restrict__ bhp,
              const unsigned short* __restrict__ h0,
              unsigned short* __restrict__ hbuf0,
              unsigned short* __restrict__ hbuf1,
              unsigned short* __restrict__ Y,
              unsigned int* __restrict__ bar,
              int B, int E, int K, int net)
{
  __shared__ __align__(16) unsigned char smem[156672];     // 153 KB
  unsigned short* Ah  = (unsigned short*)smem;             // 6 x 8KB A ring
  unsigned short* Bss = (unsigned short*)(smem + 49152);   // 3 x 24KB B ring
  unsigned short* GIs = (unsigned short*)(smem + 122880);  // 24KB
  unsigned short* Ys  = (unsigned short*)(smem + 147456);  // 9KB persistent h
  float* Red = (float*)smem;  // gate-phase alias over dead A/B-head space

  const int N3 = 3 * E;
  const int e6 = blockIdx.x;           // e6%8 -> XCD pinning of Whh panel
  const int bt = blockIdx.y;
  const int b0 = bt << 6;
  const int ec0 = e6 * 192;
  const int ecol0 = e6 << 6;
  const int tid = threadIdx.x;
  const int lane = tid & 63;
  const int w = tid >> 6;
  const int ew = w >> 1;               // e-col group (16 cols)
  const int kw = w & 1;                // K-half
  const int q = lane >> 4;
  const int l15 = lane & 15;
  const int el = (ew << 4) + l15;
  const int c8 = (kw << 2) + q;
  const int axo = (c8 ^ (l15 & 7)) << 3;
  const int bxo = (c8 ^ (el & 7)) << 3;

  const int arow = tid >> 3;
  const int ag8 = (tid & 7) ^ (arow & 7);
  const long a_goff = (long)(b0 + arow) * E + ag8 * 8;
  const int a_dst = tid * 8;
  long b_goff[3]; int b_dst[3];
#pragma unroll
  for (int i = 0; i < 3; ++i) {
    int c = i * 512 + tid;
    int row = c >> 3;
    int g8 = (c & 7) ^ (row & 7);
    b_goff[i] = (long)(ec0 + row) * E + g8 * 8;
    b_dst[i] = c * 8;
  }
  long gi_off[3]; int gi_dst[3];
#pragma unroll
  for (int i = 0; i < 3; ++i) {
    int c = i * 512 + tid;
    int row = c / 24, cc = c - row * 24;
    gi_off[i] = (long)(b0 + row) * N3 + ec0 + cc * 8;
    gi_dst[i] = c * 8;
  }

  const float bh0 = bhp[ec0 + el];
  const float bh1 = bhp[ec0 + 64 + el];
  const float bh2 = bhp[ec0 + 128 + el];

  if (kw == 0) {
#pragma unroll
    for (int m = 0; m < 4; ++m)
#pragma unroll
      for (int j = 0; j < 4; ++j) {
        int row = m * 16 + q * 4 + j;
        Ys[row * 72 + el] = h0[(long)(b0 + row) * E + ecol0 + el];
      }
  }
  __syncthreads();

  for (int k = 0; k < K; ++k) {
    const unsigned short* hprev = (k & 1) ? hbuf1 : hbuf0;
    unsigned short* hnext = (k & 1) ? hbuf0 : hbuf1;
    const unsigned short* GIk = GI + (long)k * B * N3;

    // ---- prolog issue: GI(3), A tiles 0..4 (coherent), B tiles 0,1 ----
#pragma unroll
    for (int i = 0; i < 3; ++i) gll16(GIk + gi_off[i], GIs + gi_dst[i]);
#pragma unroll
    for (int t = 0; t < 5; ++t)
      gll16u(hprev + a_goff + t * 64, Ah + t * 4096 + a_dst);
#pragma unroll
    for (int t = 0; t < 2; ++t)
#pragma unroll
      for (int i = 0; i < 3; ++i)
        gll16(Whp + b_goff[i] + t * 64, Bss + t * 12288 + b_dst[i]);

    f32x4 acc[4][3];
#pragma unroll
    for (int m = 0; m < 4; ++m)
#pragma unroll
      for (int g = 0; g < 3; ++g)
        acc[m][g] = (f32x4){0.f, 0.f, 0.f, 0.f};

#pragma unroll
    for (int kt = 0; kt < 16; ++kt) {
      if (kt == 0)       VMW(3);
      else if (kt == 1)  VMW(4);
      else if (kt <= 11) VMW(5);
      else if (kt == 12) VMW(4);
      else if (kt == 15) VMW(0);
      else               VMW(3);
      LGKM0;
      __builtin_amdgcn_s_barrier();
      CFENCE;

      if (kt + 2 < 16) {
#pragma unroll
        for (int i = 0; i < 3; ++i)
          gll16(Whp + b_goff[i] + (kt + 2) * 64,
                Bss + ((kt + 2) % 3) * 12288 + b_dst[i]);
      }
      if (kt + 5 < 16)
        gll16u(hprev + a_goff + (kt + 5) * 64,
               Ah + ((kt + 5) % 6) * 4096 + a_dst);

      const unsigned short* Ab = Ah + (kt % 6) * 4096;
      const unsigned short* Bb = Bss + (kt % 3) * 12288;
      bf16x8 af[4], bfg[3];
#pragma unroll
      for (int m = 0; m < 4; ++m)
        af[m] = *(const bf16x8*)&Ab[(m * 16 + l15) * 64 + axo];
#pragma unroll
      for (int g = 0; g < 3; ++g)
        bfg[g] = *(const bf16x8*)&Bb[(g * 64 + el) * 64 + bxo];

      __builtin_amdgcn_s_setprio(1);
#pragma unroll
      for (int g = 0; g < 3; ++g)
#pragma unroll
        for (int m = 0; m < 4; ++m)
          acc[m][g] = __builtin_amdgcn_mfma_f32_16x16x32_bf16(
              af[m], bfg[g], acc[m][g], 0, 0, 0);
      __builtin_amdgcn_s_setprio(0);
    }

    // ---- K-split reduce (Red aliases dead A/B LDS) + fused gates ----
    __syncthreads();
    float* rp = &Red[((ew << 6) + lane) * 49];
    if (kw == 1) {
#pragma unroll
      for (int m = 0; m < 4; ++m)
#pragma unroll
        for (int g = 0; g < 3; ++g)
#pragma unroll
          for (int cc = 0; cc < 4; ++cc)
            rp[(m * 3 + g) * 4 + cc] = acc[m][g][cc];
    }
    __syncthreads();
    if (kw == 0) {
#pragma unroll
      for (int m = 0; m < 4; ++m) {
#pragma unroll
        for (int j = 0; j < 4; ++j) {
          int row = m * 16 + q * 4 + j;
          float ghr = acc[m][0][j] + rp[(m * 3 + 0) * 4 + j];
          float ghz = acc[m][1][j] + rp[(m * 3 + 1) * 4 + j];
          float ghn = acc[m][2][j] + rp[(m * 3 + 2) * 4 + j];
          float gr = b2f(GIs[row * 192 + el]);
          float gz = b2f(GIs[row * 192 + 64 + el]);
          float gn = b2f(GIs[row * 192 + 128 + el]);
          float hu = b2f(Ys[row * 72 + el]);
          float r = sigm(gr + ghr + bh0);
          float z = sigm(gz + ghz + bh1);
          float n = tanh_f(gn + r * (ghn + bh2));
          float hv = (1.f - z) * n + z * hu;
          Ys[row * 72 + el] = f2b(hv);
        }
      }
    }
    __syncthreads();
    {
      int row = tid >> 3, cc = tid & 7;
      u16x8 v = *(const u16x8*)&Ys[row * 72 + cc * 8];
      unsigned* pv = (unsigned*)&v;
      unsigned long long s0 = ((unsigned long long)pv[1] << 32) | pv[0];
      unsigned long long s1 = ((unsigned long long)pv[3] << 32) | pv[2];
      unsigned short* hp = hnext + (long)(b0 + row) * E + ecol0 + cc * 8;
      as64(hp, s0);
      as64(hp + 4, s1);
      *(u16x8*)(Y + ((long)k * B + b0 + row) * E + ecol0 + cc * 8) = v;
    }
    if (k + 1 < K) {
      __syncthreads();
      if (tid == 0) {
        __hip_atomic_fetch_add(&bar[bt * 64], 1u, __ATOMIC_RELAXED,
                               __HIP_MEMORY_SCOPE_AGENT);
        unsigned target = (unsigned)(k + 1) * (unsigned)net;
        while (__hip_atomic_load(&bar[bt * 64], __ATOMIC_RELAXED,
                                 __HIP_MEMORY_SCOPE_AGENT) < target)
          __builtin_amdgcn_s_sleep(1);
      }
      __syncthreads();
    }
  }
}

// -------------------- pointwise GRU gates (fallback path) -------------
template<int YMODE>
__global__ __launch_bounds__(256)
void gru_pointwise(const unsigned short* __restrict__ GIk,
                   const float* __restrict__ gh,
                   float* __restrict__ h, unsigned short* __restrict__ hbf,
                   unsigned short* __restrict__ Yb,
                   float* __restrict__ out, int k, int B, int E, int K)
{
  long i4 = ((long)blockIdx.x * blockDim.x + threadIdx.x) * 4;
  if (i4 >= (long)B * E) return;
  long b = i4 / E;
  long e = i4 - b * E;
  long g0 = b * 3 * E + e;
  ushort4 ir = *(const ushort4*)(GIk + g0);
  ushort4 iz = *(const ushort4*)(GIk + g0 + E);
  ushort4 in4 = *(const ushort4*)(GIk + g0 + 2 * E);
  float4 hr = *(const float4*)(gh + g0);
  float4 hz = *(const float4*)(gh + g0 + E);
  float4 hn = *(const float4*)(gh + g0 + 2 * E);
  float4 hv = *(const float4*)(h + i4);

  float irf[4] = { b2f(ir.x), b2f(ir.y), b2f(ir.z), b2f(ir.w) };
  float izf[4] = { b2f(iz.x), b2f(iz.y), b2f(iz.z), b2f(iz.w) };
  float inf_[4] = { b2f(in4.x), b2f(in4.y), b2f(in4.z), b2f(in4.w) };
  float hrf[4] = { hr.x, hr.y, hr.z, hr.w };
  float hzf[4] = { hz.x, hz.y, hz.z, hz.w };
  float hnf[4] = { hn.x, hn.y, hn.z, hn.w };
  float hvf[4] = { hv.x, hv.y, hv.z, hv.w };
  float hnew[4];
#pragma unroll
  for (int j = 0; j < 4; ++j) {
    float r = sigm(irf[j] + hrf[j]);
    float z = sigm(izf[j] + hzf[j]);
    float n = tanh_f(inf_[j] + r * hnf[j]);
    hnew[j] = (1.f - z) * n + z * hvf[j];
  }
  *(float4*)(h + i4) = make_float4(hnew[0], hnew[1], hnew[2], hnew[3]);
  ushort4 hb = make_ushort4(f2b(hnew[0]), f2b(hnew[1]), f2b(hnew[2]), f2b(hnew[3]));
  *(ushort4*)(hbf + i4) = hb;
  if (YMODE == 1) {
    *(ushort4*)(Yb + ((long)k * B + b) * E + e) = hb;
  } else {
    float* o = out + (b * E + e) * K + k;
    o[0] = hnew[0]; o[K] = hnew[1]; o[2 * K] = hnew[2]; o[3 * K] = hnew[3];
  }
}

// -------------------- transpose Y (K,B,E) bf16 -> out (B,E,K) fp32 ----
__global__ __launch_bounds__(256)
void transpose_y(const unsigned short* __restrict__ Yv, float* __restrict__ out,
                 int B, int E, int K)
{
  __shared__ float T[64][65];
  int e0 = blockIdx.x * 64;
  int b = blockIdx.y;
  int t = threadIdx.x;
#pragma unroll
  for (int i = 0; i < 4; ++i) {
    int c = i * 256 + t;
    int k = c >> 4, f4 = c & 15;
    long off = ((long)k * B + b) * E + e0 + f4 * 4;
    ushort4 v = *(const ushort4*)(Yv + off);
    T[k][f4 * 4 + 0] = b2f(v.x); T[k][f4 * 4 + 1] = b2f(v.y);
    T[k][f4 * 4 + 2] = b2f(v.z); T[k][f4 * 4 + 3] = b2f(v.w);
  }
  __syncthreads();
#pragma unroll
  for (int i = 0; i < 4; ++i) {
    int c = i * 256 + t;
    int e = c >> 4, f4k = c & 15;
    float4 w;
    w.x = T[f4k * 4 + 0][e];
    w.y = T[f4k * 4 + 1][e];
    w.z = T[f4k * 4 + 2][e];
    w.w = T[f4k * 4 + 3][e];
    *(float4*)(out + ((long)b * E + e0 + e) * K + f4k * 4) = w;
  }
}

// -------------------- host launch -------------------------------------
extern "C" void kernel_launch(void* const* d_in, const int* in_sizes, int n_in,
                              void* d_out, int out_size, void* d_ws, size_t ws_size,
                              hipStream_t stream)
{
  const float* c   = (const float*)d_in[0];
  const float* x   = (const float*)d_in[1];
  const float* Wih = (const float*)d_in[2];
  const float* Whh = (const float*)d_in[3];
  const float* bih = (const float*)d_in[4];
  const float* bhh = (const float*)d_in[5];
  float* out = (float*)d_out;

  long BE = in_sizes[0];
  int E = (int)(sqrtf((float)(in_sizes[2] / 3)) + 0.5f);
  int B = (int)(BE / E);
  int K = (int)(in_sizes[1] / BE);
  int N3 = 3 * E;
  long M_GI = (long)K * B;

  char* w = (char*)d_ws;
  size_t used = 0;
  auto alloc = [&](size_t bytes) -> char* {
    char* p = w + used;
    used += (bytes + 255) & ~(size_t)255;
    return p;
  };
  unsigned short* Wihb  = (unsigned short*)alloc((size_t)N3 * E * 2);
  unsigned short* Whhb  = (unsigned short*)alloc((size_t)N3 * E * 2);
  unsigned short* hb0   = (unsigned short*)alloc((size_t)B * E * 2);
  float* h32            = (float*)alloc((size_t)B * E * 4);
  float* gh             = (float*)alloc((size_t)B * N3 * 4);
  unsigned short* GIstep= (unsigned short*)alloc((size_t)B * N3 * 2);
  unsigned short* XS    = (unsigned short*)alloc((size_t)K * B * E * 2);

  size_t rem = (ws_size > used) ? ws_size - used : 0;
  size_t szW   = (((size_t)N3 * E * 2) + 255) & ~(size_t)255;
  size_t szB3  = (((size_t)N3 * 4) + 255) & ~(size_t)255;
  size_t szHb1 = (((size_t)B * E * 2) + 255) & ~(size_t)255;
  size_t szGI  = (((size_t)K * B * N3 * 2) + 255) & ~(size_t)255;
  size_t szY   = (((size_t)K * B * E * 2) + 255) & ~(size_t)255;
  int nbt = B / 64, net = E / 64;
  size_t szBar = ((size_t)nbt * 64 * 4 + 255) & ~(size_t)255;

  bool canFused = (B == 1024) && (E == 1024) &&
                  (rem >= 2 * szW + 2 * szB3 + szHb1 + szGI + szY + szBar);

  long nW = (long)N3 * E;
  prep_kernel<<<dim3(2048), dim3(256), 0, stream>>>(Wih, Whh, c, Wihb, Whhb,
                                                    hb0, h32, nW, BE);
  hipMemsetAsync(XS, 0, (size_t)B * E * 2, stream);
  transpose_x<<<dim3(E / 64, B), dim3(256), 0, stream>>>(x, XS, B, E, K);

  if (canFused) {
    unsigned short* Wihp = (unsigned short*)alloc(szW);
    unsigned short* Whhp = (unsigned short*)alloc(szW);
    float* bihp          = (float*)alloc(szB3);
    float* bhhp          = (float*)alloc(szB3);
    unsigned short* hb1  = (unsigned short*)alloc(szHb1);
    unsigned short* GI   = (unsigned short*)alloc(szGI);
    unsigned short* Yb   = (unsigned short*)alloc(szY);
    unsigned int*   bar  = (unsigned int*)alloc(szBar);

    reorder_kernel<<<dim3(2048), dim3(256), 0, stream>>>(
        Wihb, Whhb, bih, bhh, Wihp, Whhp, bihp, bhhp, E);

    // GI GEMM: M=K*B=65536 (128-tiles), N=3072 (256-tiles), K=1024
    gemm256<<<dim3(N3 / 256, (int)(M_GI / 128)), dim3(512), 0, stream>>>(
        XS, Wihp, bihp, GI, (int)M_GI, N3, E);
    hipMemsetAsync(bar, 0, szBar, stream);

    const unsigned short* GIc = GI;
    const unsigned short* Whhc = Whhp;
    const float* bhhc = bhhp;
    const unsigned short* h0c = hb0;
    void* args[] = { (void*)&GIc, (void*)&Whhc, (void*)&bhhc, (void*)&h0c,
                     (void*)&hb0, (void*)&hb1, (void*)&Yb,
                     (void*)&bar, (void*)&B, (void*)&E, (void*)&K, (void*)&net };
    hipError_t ce = hipLaunchCooperativeKernel(
        (const void*)gru_rec4, dim3(net, nbt), dim3(512), args, 0, stream);
    if (ce != hipSuccess) {
      (void)hipGetLastError();
      gru_rec4<<<dim3(net, nbt), dim3(512), 0, stream>>>(
          GIc, Whhc, bhhc, h0c, hb0, hb1, Yb, bar, B, E, K, net);
    }
    transpose_y<<<dim3(E / 64, B), dim3(256), 0, stream>>>(Yb, out, B, E, K);
    return;
  }

  // -------- fallback: per-step GEMMs (round-1 path, normal layout) -----
  int haveY = rem >= szY;
  unsigned short* Yb = haveY ? (unsigned short*)alloc(szY) : nullptr;
  int pgrid = (int)((BE / 4 + 255) / 256);
  for (int k = 0; k < K; ++k) {
    gemm_bt<1><<<dim3(N3 / BN, B / BM), dim3(256), 0, stream>>>(
        XS + (size_t)k * B * E, Wihb, bih, nullptr, GIstep, B, N3, E);
    gemm_bt<0><<<dim3(N3 / BN, B / BM), dim3(256), 0, stream>>>(
        hb0, Whhb, bhh, gh, nullptr, B, N3, E);
    if (haveY)
      gru_pointwise<1><<<dim3(pgrid), dim3(256), 0, stream>>>(
          GIstep, gh, h32, hb0, Yb, out, k, B, E, K);
    else
      gru_pointwise<2><<<dim3(pgrid), dim3(256), 0, stream>>>(
          GIstep, gh, h32, hb0, nullptr, out, k, B, E, K);
  }
  if (haveY)
    transpose_y<<<dim3(E / 64, B), dim3(256), 0, stream>>>(Yb, out, B, E, K);
}